// Round 11
// baseline (122.545 us; speedup 1.0000x reference)
//
#include <hip/hip_runtime.h>

// ---------------------------------------------------------------------------
// MultiScaleResidualVectorQuantize: 4-stage residual VQ, strides (8,4,2,1)
// e_i = P_i - sum_{j<i} row_ij(idx_j);  P_i = iw_i*pool_i(z)+ib_i;
// row_ij(code) = f32(M_ij*cb_j[code]+v_ij) (f64 dot, f32 round) -- computed
// per-block on the fly into LDS at stage-merge time (winner thread computes
// its own rows) -> no global tab, no tabgen launch.
// 3 launches: [pool+prep] -> vq_all (fused cascade, nested block windows)
// -> zq.
// ---------------------------------------------------------------------------

constexpr int B = 16, D = 512, T = 4096, C = 8, K = 1024, NS = 4;

// output offsets (floats, reference return order)
constexpr long long OUT_ZQ     = 0;                       // 16*512*4096
constexpr long long OUT_LAT    = 33554432LL;              // 16*32*4096
constexpr long long OUT_COMMIT = OUT_LAT + 2097152LL;
constexpr long long OUT_CBL    = OUT_COMMIT + 1;
constexpr long long OUT_CODES0 = OUT_CBL + 1;

__host__ __device__ constexpr long long code_off(int j) {
    return OUT_CODES0 + (j >= 1 ? 8192 : 0) + (j >= 2 ? 16384 : 0) + (j >= 3 ? 32768 : 0);
}

// workspace offsets (floats / 4B units)
constexpr long long WS_CBREC = 0;                 // [4096][8] = -2*cn
constexpr long long WS_CN2   = 32768;             // [4096]
constexpr long long WS_OBS   = 36864;             // 512
constexpr long long WS_LOSS  = 37376;             // 1
constexpr long long WS_CORR  = 37384;             // 1152 doubles (8B aligned)
constexpr long long WS_P0    = 40960;             // 8192*8
constexpr long long WS_P1    = WS_P0 + 65536;
constexpr long long WS_P2    = WS_P1 + 131072;
constexpr long long WS_P3    = WS_P2 + 262144;
constexpr long long WS_IDX   = WS_P3 + 524288;    // 122880 ints; ends ~4.6MB

__host__ __device__ constexpr long long idx_off(int s) {  // int units
    return (s >= 1 ? 8192 : 0) + (s >= 2 ? 16384 : 0) + (s >= 3 ? 32768 : 0);
}
__host__ __device__ constexpr long long pbase_of(int s) {
    return (s == 0) ? WS_P0 : (s == 1) ? WS_P1 : (s == 2) ? WS_P2 : WS_P3;
}

// ---------------------------------------------------------------------------
// k_pool_prep: bid<256 -> pooled projections (256-t span, float4 z loads);
// 256..264 -> packed records (-2cn, cn2) + obs + loss=0;
// 265..318 -> correction terms M_ij/v_ij (f64, one wave per scalar).
// All prep outputs consumed only by later kernels -> no intra-kernel race.
// ---------------------------------------------------------------------------
__global__ __launch_bounds__(512) void k_pool_prep(
    const float* __restrict__ z, const float* __restrict__ in_w,
    const float* __restrict__ in_b, const float* __restrict__ out_w,
    const float* __restrict__ out_b, const float* __restrict__ cb,
    float* __restrict__ ws)
{
    __shared__ float smem[512 * 36];     // 72 KB: in_w [d][36], later reduction tree

    int bid = blockIdx.x;
    int tid = threadIdx.x;
    int lane = tid & 63;

    if (bid >= 256) {
        if (bid < 265) {
            // --- records + obs + loss zero ---
            int t = (bid - 256) * 512 + tid;
            if (t == 0) ws[WS_LOSS] = 0.f;
            if (t < NS * K) {
                const float* c = cb + (long long)t * 8;
                float cv[8];
#pragma unroll
                for (int k = 0; k < 8; k++) cv[k] = c[k];
                float n2 = 0.f;
#pragma unroll
                for (int k = 0; k < 8; k++) n2 += cv[k] * cv[k];
                float den = fmaxf(sqrtf(n2), 1e-12f);
                float cn[8];
#pragma unroll
                for (int k = 0; k < 8; k++) cn[k] = cv[k] / den;
                float cn2 = 0.f;
#pragma unroll
                for (int k = 0; k < 8; k++) cn2 = fmaf(cn[k], cn[k], cn2);
                float* r = ws + WS_CBREC + (long long)t * 8;
#pragma unroll
                for (int k = 0; k < 8; k++) r[k] = -2.0f * cn[k];
                ws[WS_CN2 + t] = cn2;
            } else if (t < NS * K + D) {
                int d = t - NS * K;
                ws[WS_OBS + d] = out_b[d] + out_b[512 + d] + out_b[1024 + d] + out_b[1536 + d];
            }
        } else {
            // --- correction terms (f64), 432 waves ---
            int gw = (bid - 265) * 8 + (tid >> 6);
            if (gw >= 6 * 72) return;
            int p = gw / 72, idx = gw % 72;
            int i, j;
            if (p == 0) { i = 1; j = 0; }
            else if (p < 3) { i = 2; j = p - 1; }
            else { i = 3; j = p - 3; }

            double acc = 0.0;
            if (idx < 64) {
                int ci = idx >> 3, cc = idx & 7;
                const float* wi = in_w + (long long)(i * 8 + ci) * 512;
                const float* wo = out_w + (long long)j * 4096;      // [d][8]
#pragma unroll
                for (int k = 0; k < 8; k++) {
                    int d = lane + k * 64;
                    acc += (double)wi[d] * (double)wo[d * 8 + cc];
                }
            } else {
                int ci = idx - 64;
                const float* wi = in_w + (long long)(i * 8 + ci) * 512;
                const float* bo = out_b + (long long)j * 512;
#pragma unroll
                for (int k = 0; k < 8; k++) {
                    int d = lane + k * 64;
                    acc += (double)wi[d] * (double)bo[d];
                }
            }
#pragma unroll
            for (int off = 32; off >= 1; off >>= 1) acc += __shfl_down(acc, off);
            if (lane == 0) ((double*)(ws + WS_CORR))[p * 72 + idx] = acc;
        }
        return;
    }

    // --- pool part: b = bid&15, 256-t span, lane owns 4 consecutive t ---
    int wv = __builtin_amdgcn_readfirstlane(tid >> 6);
    int b = bid & 15;
    int t0 = (bid >> 4) * 256;

#pragma unroll
    for (int sc = 0; sc < 32; ++sc)
        smem[tid * 36 + sc] = in_w[sc * 512 + tid];
    __syncthreads();

    const float* zrow = z + ((long long)b * D) * T + t0 + lane * 4;

    float a3[4][8] = {};
    float a2[2][8] = {};
    float a1[8]    = {};
    float a0[8]    = {};

#pragma unroll 2
    for (int dd = 0; dd < 64; dd++) {
        int d = wv * 64 + dd;
        float4 v = *(const float4*)(zrow + (long long)d * T);
        const float* wrow = smem + d * 36;
        float w0[8], w1[8], w2[8], w3[8];
        *(float4*)&w0[0] = *(const float4*)(wrow + 0);
        *(float4*)&w0[4] = *(const float4*)(wrow + 4);
        *(float4*)&w1[0] = *(const float4*)(wrow + 8);
        *(float4*)&w1[4] = *(const float4*)(wrow + 12);
        *(float4*)&w2[0] = *(const float4*)(wrow + 16);
        *(float4*)&w2[4] = *(const float4*)(wrow + 20);
        *(float4*)&w3[0] = *(const float4*)(wrow + 24);
        *(float4*)&w3[4] = *(const float4*)(wrow + 28);

        float s2a = v.x + v.y, s2b = v.z + v.w;
        float s4 = s2a + s2b;
#pragma unroll
        for (int c = 0; c < 8; c++) {
            a3[0][c] = fmaf(w3[c], v.x, a3[0][c]);
            a3[1][c] = fmaf(w3[c], v.y, a3[1][c]);
            a3[2][c] = fmaf(w3[c], v.z, a3[2][c]);
            a3[3][c] = fmaf(w3[c], v.w, a3[3][c]);
            a2[0][c] = fmaf(w2[c], s2a, a2[0][c]);
            a2[1][c] = fmaf(w2[c], s2b, a2[1][c]);
            a1[c]    = fmaf(w1[c], s4, a1[c]);
            a0[c]    = fmaf(w0[c], s4, a0[c]);
        }
    }

    __syncthreads();   // done reading in_w slice; alias smem as tree

    // round 1: stage3 (32 slots), red[8][32][64] = 64KB fits the 72KB buffer
    {
        float (*red)[32][64] = (float (*)[32][64])smem;
#pragma unroll
        for (int pos = 0; pos < 4; pos++)
#pragma unroll
            for (int c = 0; c < 8; c++)
                red[wv][pos * 8 + c][lane] = a3[pos][c];
        __syncthreads();
        for (int o = tid; o < 2048; o += 512) {
            int ln = o & 63, s = o >> 6;
            float sum = 0.f;
#pragma unroll
            for (int w = 0; w < 8; w++) sum += red[w][s][ln];
            int pos = s >> 3, c = s & 7;
            int tp = t0 + ln * 4 + pos;
            ws[WS_P3 + ((long long)b * 4096 + tp) * 8 + c] = sum + in_b[3 * 8 + c];
        }
        __syncthreads();
    }

    // round 2: stage2 (16 slots), stage1 (8), stage0 (8, lane-pair merge)
    {
        float (*red)[32][64] = (float (*)[32][64])smem;
#pragma unroll
        for (int pos = 0; pos < 2; pos++)
#pragma unroll
            for (int c = 0; c < 8; c++)
                red[wv][pos * 8 + c][lane] = a2[pos][c];
#pragma unroll
        for (int c = 0; c < 8; c++) {
            red[wv][16 + c][lane] = a1[c];
            red[wv][24 + c][lane] = a0[c];
        }
        __syncthreads();
        for (int o = tid; o < 2048; o += 512) {
            int ln = o & 63, s = o >> 6;
            if (s < 16) {
                float sum = 0.f;
#pragma unroll
                for (int w = 0; w < 8; w++) sum += red[w][s][ln];
                int pos = s >> 3, c = s & 7;
                int tp = (t0 >> 1) + ln * 2 + pos;
                ws[WS_P2 + ((long long)b * 2048 + tp) * 8 + c] = sum * 0.5f + in_b[2 * 8 + c];
            } else if (s < 24) {
                int c = s - 16;
                float sum = 0.f;
#pragma unroll
                for (int w = 0; w < 8; w++) sum += red[w][s][ln];
                int tp = (t0 >> 2) + ln;
                ws[WS_P1 + ((long long)b * 1024 + tp) * 8 + c] = sum * 0.25f + in_b[8 + c];
            } else {
                if (ln & 1) continue;
                int c = s - 24;
                float sum = 0.f;
#pragma unroll
                for (int w = 0; w < 8; w++) sum += red[w][s][ln] + red[w][s][ln + 1];
                int tp = (t0 >> 3) + (ln >> 1);
                ws[WS_P0 + ((long long)b * 512 + tp) * 8 + c] = sum * 0.125f + in_b[c];
            }
        }
    }
}

// ---------------------------------------------------------------------------
// k_vq_all: fused 4-stage cascade. 256 blocks x 1024 thr (16 waves, 4/SIMD).
// Per stage: records->LDS, e-compute (LDS corr rows, f64), latents, 16-wave
// x 64-code scan (VPL<=4), LDS merge (exact first-index ties), winner thread
// computes next-stages' corr rows for ITS code into LDS (f64 dot, f32 round
// -- bit-identical to global tabgen). 1 loss atomic/block.
// ltab rows: p0@0(32) p1@32(32) p2@64(64) p3@128(32) p4@160(64) p5@224(128).
// ---------------------------------------------------------------------------
__device__ __forceinline__ void corr_row(
    const double* __restrict__ M, const float* __restrict__ q, float* __restrict__ dst)
{
#pragma unroll
    for (int c = 0; c < 8; c++) {
        double acc = M[64 + c];
#pragma unroll
        for (int cc = 0; cc < 8; cc++) acc += M[c * 8 + cc] * (double)q[cc];
        dst[c] = (float)acc;
    }
}

template <int S>
__device__ __forceinline__ void vq_stage_all(
    int tid, int lane, int w, int bid,
    const float* __restrict__ cb, float* __restrict__ ws, float* __restrict__ out,
    float* __restrict__ recl, float* __restrict__ cn2l,
    float (&e_lds)[256][8], float (&en_lds)[256][8],
    float (&sbl)[16][256], unsigned short (&sil)[16][256],
    int* __restrict__ idxl, float (&ltab)[352][8], float& loss_acc)
{
    constexpr int NV = 32 << S;
    constexpr int TS = 512 << S;
    constexpr long long PB = pbase_of(S);
    constexpr int pbase = (S == 1) ? 0 : (S == 2) ? 1 : 3;
    constexpr int VPL = (NV >= 64) ? (NV / 64) : 1;
    constexpr float LW = 1.0f / (float)(65536 << S);
    constexpr int PBARR[6] = { 0, 32, 64, 128, 160, 224 };

    // A: stage records -> LDS
    {
        const float4* rs = (const float4*)(ws + WS_CBREC + (long long)S * 8192);
        float4* rd = (float4*)recl;
        rd[tid] = rs[tid];
        rd[tid + 1024] = rs[tid + 1024];
        if (tid < 256)
            ((float4*)cn2l)[tid] = ((const float4*)(ws + WS_CN2 + (long long)S * 1024))[tid];
    }

    // B: e-compute (one thread per vector); corr rows from LDS (prev stages)
    if (tid < NV) {
        long long gv = (long long)bid * NV + tid;
        float e[8];
        const float* P = ws + PB + gv * 8;
        *(float4*)&e[0] = *(const float4*)(P + 0);
        *(float4*)&e[4] = *(const float4*)(P + 4);

        if constexpr (S > 0) {
            double ed[8];
#pragma unroll
            for (int c = 0; c < 8; c++) ed[c] = (double)e[c];
#pragma unroll
            for (int j = 0; j < S; j++) {
                const float* trow = ltab[PBARR[pbase + j] + (tid >> (S - j))];
#pragma unroll
                for (int c = 0; c < 8; c++) ed[c] -= (double)trow[c];
            }
#pragma unroll
            for (int c = 0; c < 8; c++) e[c] = (float)ed[c];
        }

        float n2 = 0.f;
#pragma unroll
        for (int c = 0; c < 8; c++) n2 = fmaf(e[c], e[c], n2);
        float den = fmaxf(sqrtf(n2), 1e-12f);
        float inv = 1.0f / den;
#pragma unroll
        for (int c = 0; c < 8; c++) {
            e_lds[tid][c] = e[c];
            en_lds[tid][c] = e[c] * inv;
        }
    }
    __syncthreads();   // recl, cn2l, e_lds, en_lds ready

    // C: latents (2048 floats, 2 per thread, coalesced float2)
    {
        constexpr int SREP = 8 >> S;
        constexpr int SH = 3 - S;
        long long gv0 = (long long)bid * NV;
        int b0 = (int)(gv0 >> (9 + S));
        int tp0 = (int)(gv0 & (TS - 1));
        long long lat0 = OUT_LAT + ((long long)b0 * 32 + S * 8) * T + (long long)tp0 * SREP;
        int o = tid * 2;
        int c = o >> 8, r = o & 255;
        *(float2*)(out + lat0 + (long long)c * T + r) =
            make_float2(e_lds[r >> SH][c], e_lds[(r + 1) >> SH][c]);
    }

    // D: scan -- wave w covers codes [w*64, w*64+64) for VPL vectors/lane
    float en_r[VPL][8];
#pragma unroll
    for (int v = 0; v < VPL; v++) {
        int sv = (NV >= 64) ? (v * 64 + lane) : (lane & (NV - 1));
#pragma unroll
        for (int c = 0; c < 8; c++) en_r[v][c] = en_lds[sv][c];
    }
    const float* rec = recl + w * 64 * 8;
    const float* c2 = cn2l + w * 64;
    float best[VPL];
    int bi[VPL];
#pragma unroll
    for (int v = 0; v < VPL; v++) { best[v] = 3.0e38f; bi[v] = 0; }

    for (int j0 = 0; j0 < 64; j0 += 4) {
        float4 cq = *(const float4*)(c2 + j0);
        float cqa[4] = { cq.x, cq.y, cq.z, cq.w };
#pragma unroll
        for (int k = 0; k < 4; k++) {
            int jt = j0 + k;
            const float* r = rec + jt * 8;
            float rr[8];
            *(float4*)&rr[0] = *(const float4*)(r + 0);
            *(float4*)&rr[4] = *(const float4*)(r + 4);
            float acc[VPL];
#pragma unroll
            for (int v = 0; v < VPL; v++) acc[v] = cqa[k];
#pragma unroll
            for (int c = 0; c < 8; c++) {
                float rc = rr[c];
#pragma unroll
                for (int v = 0; v < VPL; v++) acc[v] = fmaf(rc, en_r[v][c], acc[v]);
            }
#pragma unroll
            for (int v = 0; v < VPL; v++)
                if (acc[v] < best[v]) { best[v] = acc[v]; bi[v] = jt; }
        }
    }

    // E: per-wave results
#pragma unroll
    for (int v = 0; v < VPL; v++) {
        int sv = (NV >= 64) ? (v * 64 + lane) : (lane & (NV - 1));
        sbl[w][sv] = best[v];
        sil[w][sv] = (unsigned short)(w * 64 + bi[v]);
    }
    __syncthreads();

    // F: merge (w ascending = code ascending -> exact first-index ties),
    //    winner outputs + on-the-fly corr rows for this stage's code.
    if (tid < NV) {
        float bd = sbl[0][tid];
        int bj = sil[0][tid];
#pragma unroll
        for (int ww = 1; ww < 16; ww++) {
            float d2 = sbl[ww][tid];
            int j2 = sil[ww][tid];
            if (d2 < bd || (d2 == bd && j2 < bj)) { bd = d2; bj = j2; }
        }
        if constexpr (S == 0) idxl[tid] = bj;
        else if constexpr (S == 1) idxl[32 + tid] = bj;
        else if constexpr (S == 2) idxl[96 + tid] = bj;

        long long gv = (long long)bid * NV + tid;
        out[code_off(S) + gv] = (float)bj;
        ((int*)ws)[WS_IDX + idx_off(S) + gv] = bj;

        const float* qc = cb + ((long long)S * K + bj) * 8;
        float qv[8];
#pragma unroll
        for (int c = 0; c < 8; c++) qv[c] = qc[c];

        float l = 0.f;
#pragma unroll
        for (int c = 0; c < 8; c++) {
            float dq = e_lds[tid][c] - qv[c];
            l = fmaf(dq, dq, l);
        }
        loss_acc += l * LW;

        // corr rows for pairs sourced at stage S (consumed by stages > S)
        const double* corrd = (const double*)(ws + WS_CORR);
        if constexpr (S == 0) {
            corr_row(corrd + 0 * 72, qv, ltab[0 + tid]);     // p0 (1,0)
            corr_row(corrd + 1 * 72, qv, ltab[32 + tid]);    // p1 (2,0)
            corr_row(corrd + 3 * 72, qv, ltab[128 + tid]);   // p3 (3,0)
        } else if constexpr (S == 1) {
            corr_row(corrd + 2 * 72, qv, ltab[64 + tid]);    // p2 (2,1)
            corr_row(corrd + 4 * 72, qv, ltab[160 + tid]);   // p4 (3,1)
        } else if constexpr (S == 2) {
            corr_row(corrd + 5 * 72, qv, ltab[224 + tid]);   // p5 (3,2)
        }
    }
    __syncthreads();   // idxl + ltab ready for next stage; recl reusable
}

__global__ __launch_bounds__(1024) void k_vq_all(
    const float* __restrict__ cb, float* __restrict__ ws, float* __restrict__ out)
{
    __shared__ float recl[1024 * 8];        // 32 KB
    __shared__ float cn2l[1024];            // 4 KB
    __shared__ float e_lds[256][8];         // 8 KB
    __shared__ float en_lds[256][8];        // 8 KB
    __shared__ float sbl[16][256];          // 16 KB
    __shared__ unsigned short sil[16][256]; // 8 KB
    __shared__ int idxl[224];
    __shared__ float ltab[352][8];          // 11.3 KB corr rows
    __shared__ float lossw[16];

    int tid = threadIdx.x;
    int lane = tid & 63;
    int w = __builtin_amdgcn_readfirstlane(tid >> 6);
    int bid = blockIdx.x;
    float loss_acc = 0.f;

    vq_stage_all<0>(tid, lane, w, bid, cb, ws, out, recl, cn2l, e_lds, en_lds, sbl, sil, idxl, ltab, loss_acc);
    vq_stage_all<1>(tid, lane, w, bid, cb, ws, out, recl, cn2l, e_lds, en_lds, sbl, sil, idxl, ltab, loss_acc);
    vq_stage_all<2>(tid, lane, w, bid, cb, ws, out, recl, cn2l, e_lds, en_lds, sbl, sil, idxl, ltab, loss_acc);
    vq_stage_all<3>(tid, lane, w, bid, cb, ws, out, recl, cn2l, e_lds, en_lds, sbl, sil, idxl, ltab, loss_acc);

#pragma unroll
    for (int off = 32; off >= 1; off >>= 1) loss_acc += __shfl_down(loss_acc, off);
    if (lane == 0) lossw[w] = loss_acc;
    __syncthreads();
    if (tid == 0) {
        float s = 0.f;
#pragma unroll
        for (int i = 0; i < 16; i++) s += lossw[i];
        atomicAdd(ws + WS_LOSS, s);
    }
}

// ---------------------------------------------------------------------------
// k_zq: lane owns 4 consecutive t -> float4 stores; q gathered from cb via
// int idx arrays. 4096 blocks. Same per-element FMA chain (bit-identical).
// ---------------------------------------------------------------------------
__global__ __launch_bounds__(256) void k_zq(
    const float* __restrict__ out_w, const float* __restrict__ cb,
    const float* __restrict__ ws, float* __restrict__ out)
{
    int tid = threadIdx.x;
    int lane = tid & 63;
    int w = __builtin_amdgcn_readfirstlane(tid >> 6);
    int bid = blockIdx.x;                 // 4096 = 16 b * 64 dgrp * 4 tchunk
    int tc   = bid & 3;
    int g    = (bid >> 2) & 63;
    int b    = bid >> 8;
    int t    = tc * 1024 + w * 256 + lane * 4;

    const int* wsi = (const int*)ws;

    float q0[8], q1[8], q2[2][8], q3[4][8];
    {
        int bj = wsi[WS_IDX + idx_off(0) + (long long)b * 512 + (t >> 3)];
        const float* Q = cb + (long long)bj * 8;
#pragma unroll
        for (int c = 0; c < 8; c++) q0[c] = Q[c];
    }
    {
        int bj = wsi[WS_IDX + idx_off(1) + (long long)b * 1024 + (t >> 2)];
        const float* Q = cb + (long long)(K + bj) * 8;
#pragma unroll
        for (int c = 0; c < 8; c++) q1[c] = Q[c];
    }
#pragma unroll
    for (int j = 0; j < 2; j++) {
        int bj = wsi[WS_IDX + idx_off(2) + (long long)b * 2048 + (t >> 1) + j];
        const float* Q = cb + (long long)(2 * K + bj) * 8;
#pragma unroll
        for (int c = 0; c < 8; c++) q2[j][c] = Q[c];
    }
#pragma unroll
    for (int j = 0; j < 4; j++) {
        int bj = wsi[WS_IDX + idx_off(3) + (long long)b * 4096 + t + j];
        const float* Q = cb + (long long)(3 * K + bj) * 8;
#pragma unroll
        for (int c = 0; c < 8; c++) q3[j][c] = Q[c];
    }

#pragma unroll 2
    for (int dl = 0; dl < 8; dl++) {
        int d = g * 8 + dl;
        const float* w0 = out_w + 0 * 4096 + d * 8;
        const float* w1 = out_w + 1 * 4096 + d * 8;
        const float* w2 = out_w + 2 * 4096 + d * 8;
        const float* w3 = out_w + 3 * 4096 + d * 8;

        float acc = ws[WS_OBS + d];
#pragma unroll
        for (int c = 0; c < 8; c++) acc = fmaf(w0[c], q0[c], acc);
#pragma unroll
        for (int c = 0; c < 8; c++) acc = fmaf(w1[c], q1[c], acc);
        float accA = acc, accB = acc;
#pragma unroll
        for (int c = 0; c < 8; c++) {
            accA = fmaf(w2[c], q2[0][c], accA);
            accB = fmaf(w2[c], q2[1][c], accB);
        }
        float r0 = accA, r1 = accA, r2 = accB, r3 = accB;
#pragma unroll
        for (int c = 0; c < 8; c++) {
            r0 = fmaf(w3[c], q3[0][c], r0);
            r1 = fmaf(w3[c], q3[1][c], r1);
            r2 = fmaf(w3[c], q3[2][c], r2);
            r3 = fmaf(w3[c], q3[3][c], r3);
        }
        float* o = out + OUT_ZQ + ((long long)b * 512 + d) * T + t;
        *(float4*)o = make_float4(r0, r1, r2, r3);
    }

    if (bid == 0 && tid == 0) {
        float L = ws[WS_LOSS];
        out[OUT_COMMIT] = L;
        out[OUT_CBL]    = L;
    }
}

// ---------------------------------------------------------------------------
extern "C" void kernel_launch(void* const* d_in, const int* in_sizes, int n_in,
                              void* d_out, int out_size, void* d_ws, size_t ws_size,
                              hipStream_t stream)
{
    const float* z     = (const float*)d_in[0];
    const float* in_w  = (const float*)d_in[1];
    const float* in_b  = (const float*)d_in[2];
    const float* out_w = (const float*)d_in[3];
    const float* out_b = (const float*)d_in[4];
    const float* cb    = (const float*)d_in[5];
    float* out = (float*)d_out;
    float* ws  = (float*)d_ws;

    k_pool_prep<<<dim3(319), dim3(512), 0, stream>>>(z, in_w, in_b, out_w, out_b, cb, ws);
    k_vq_all<<<dim3(256), dim3(1024), 0, stream>>>(cb, ws, out);
    k_zq<<<dim3(4096), dim3(256), 0, stream>>>(out_w, cb, ws, out);
}